// Round 3
// baseline (200.605 us; speedup 1.0000x reference)
//
#include <hip/hip_runtime.h>

#define B_N 4096
#define M_N 3
#define D_N 256
#define LOG2E 1.44269504088896340736f
#define LN2   0.69314718055994530942f
#define C_OFF   64.0f
#define T_CLAMP 112.0f

typedef __bf16 bf16x8 __attribute__((ext_vector_type(8)));
typedef float  f32x4  __attribute__((ext_vector_type(4)));

__device__ __forceinline__ unsigned short f2bf(float f) {
    unsigned int u = __float_as_uint(f);
    u += 0x7FFFu + ((u >> 16) & 1u);   // round-to-nearest-even
    return (unsigned short)(u >> 16);
}
__device__ __forceinline__ float bf2f(unsigned short h) {
    return __uint_as_float(((unsigned int)h) << 16);
}

// tokens [i][m][d] f32 -> tokb [m][i][d] bf16; norm2[m*B+i] = sum(bf16(x)^2) fp32
__global__ void cvt_kernel(const float* __restrict__ in, unsigned short* __restrict__ out,
                           float* __restrict__ norm2) {
    int idx = blockIdx.x * blockDim.x + threadIdx.x;   // 786432 float4s
    float4 v = reinterpret_cast<const float4*>(in)[idx];
    int i   = idx / 192;            // 192 = M*D/4
    int rem = idx - i * 192;
    int m   = rem >> 6;
    int d4  = rem & 63;
    ushort4 o;
    o.x = f2bf(v.x); o.y = f2bf(v.y); o.z = f2bf(v.z); o.w = f2bf(v.w);
    reinterpret_cast<ushort4*>(out)[((size_t)m * B_N + i) * 64 + d4] = o;
    float nx = bf2f(o.x), ny = bf2f(o.y), nz = bf2f(o.z), nw = bf2f(o.w);
    float s = nx * nx + ny * ny + nz * nz + nw * nw;
#pragma unroll
    for (int msk = 1; msk < 64; msk <<= 1) s += __shfl_xor(s, msk);
    if ((threadIdx.x & 63) == 0) norm2[m * B_N + i] = s;  // wave spans one (i,m) row
}

__global__ void hist_kernel(const int* __restrict__ labels, int* __restrict__ hist,
                            int* __restrict__ nvout) {
    __shared__ int h[32];
    __shared__ int nv;
    int tid = threadIdx.x;
    if (tid < 32) h[tid] = 0;
    if (tid == 0) nv = 0;
    __syncthreads();
    for (int i = tid; i < B_N; i += 256) atomicAdd(&h[labels[i]], 1);
    __syncthreads();
    int cnt = 0;
    for (int i = tid; i < B_N; i += 256) cnt += (h[labels[i]] >= 2) ? 1 : 0;
    atomicAdd(&nv, cnt);
    __syncthreads();
    if (tid < 32) hist[tid] = h[tid];
    if (tid == 0) nvout[0] = nv;
}

// Block: 128 rows x 512 cols of one modality; 4 waves x 32 rows.
// B fragments per-lane from global (L1/L2-resident), register double-buffered.
// grid = 3m x 8ns x 32rb = 768 blocks.
__global__ __launch_bounds__(256, 2) void main_kernel(
    const unsigned short* __restrict__ tokb, const int* __restrict__ labels,
    float2* __restrict__ partials) {
    int raw = blockIdx.x;
    int bid = (raw & 7) * 96 + (raw >> 3);   // bijective XCD swizzle (768 % 8 == 0)
    int m  = bid >> 8;
    int ns = (bid >> 5) & 7;
    int rb = bid & 31;
    int i0 = rb * 128;
    int cb = ns * 512;

    int tid  = threadIdx.x;
    int wave = tid >> 6, lane = tid & 63;
    int lr = lane & 15, lk = lane >> 4;
    const unsigned short* tm = tokb + (size_t)m * (B_N * D_N);

    // A fragments: rows r0 + rt*16 + lr, registers for whole kernel
    int r0 = i0 + wave * 32;
    bf16x8 afrag[2][8];
#pragma unroll
    for (int rt = 0; rt < 2; ++rt) {
        const unsigned short* rp = tm + (size_t)(r0 + rt * 16 + lr) * D_N + lk * 8;
#pragma unroll
        for (int kf = 0; kf < 8; ++kf)
            afrag[rt][kf] = *reinterpret_cast<const bf16x8*>(rp + kf * 32);
    }
    int labr[2][4];
#pragma unroll
    for (int rt = 0; rt < 2; ++rt)
#pragma unroll
        for (int j = 0; j < 4; ++j)
            labr[rt][j] = labels[r0 + rt * 16 + lk * 4 + j];

    float S[2][4] = {{0.f, 0.f, 0.f, 0.f}, {0.f, 0.f, 0.f, 0.f}};
    float P[2][4] = {{0.f, 0.f, 0.f, 0.f}, {0.f, 0.f, 0.f, 0.f}};

    // lane's B column at step kb: col cb + kb*16 + lr, elements kf*32 + lk*8 + [0,8)
    const unsigned short* bptr = tm + (size_t)(cb + lr) * D_N + lk * 8;

#define PROCESS(KB, BUF)                                                            \
    {                                                                               \
        int kb_ = (KB);                                                             \
        int labc = labels[cb + kb_ * 16 + lr];                                      \
        f32x4 acc0 = {0.f, 0.f, 0.f, 0.f};                                          \
        f32x4 acc1 = {0.f, 0.f, 0.f, 0.f};                                          \
        _Pragma("unroll")                                                           \
        for (int kf = 0; kf < 8; ++kf) {                                            \
            acc0 = __builtin_amdgcn_mfma_f32_16x16x32_bf16(afrag[0][kf], BUF[kf],   \
                                                           acc0, 0, 0, 0);          \
            acc1 = __builtin_amdgcn_mfma_f32_16x16x32_bf16(afrag[1][kf], BUF[kf],   \
                                                           acc1, 0, 0, 0);          \
        }                                                                           \
        int cg0 = cb + kb_ * 16;                                                    \
        if ((cg0 < r0 + 32) && (cg0 + 16 > r0)) {                                   \
            int colg = cg0 + lr;                                                    \
            _Pragma("unroll")                                                       \
            for (int rt = 0; rt < 2; ++rt) {                                        \
                f32x4 aa = rt ? acc1 : acc0;                                        \
                _Pragma("unroll")                                                   \
                for (int j = 0; j < 4; ++j) {                                       \
                    float s = aa[j];                                                \
                    float t = fminf(fmaf(s, LOG2E, -C_OFF), T_CLAMP);                \
                    float e = __builtin_amdgcn_exp2f(t);                            \
                    int row = r0 + rt * 16 + lk * 4 + j;                            \
                    e = (colg == row) ? 0.f : e;  /* exclude self from partition */ \
                    S[rt][j] += e;                                                  \
                    P[rt][j] += (labc == labr[rt][j]) ? s : 0.f;                    \
                }                                                                   \
            }                                                                       \
        } else {                                                                    \
            _Pragma("unroll")                                                       \
            for (int rt = 0; rt < 2; ++rt) {                                        \
                f32x4 aa = rt ? acc1 : acc0;                                        \
                _Pragma("unroll")                                                   \
                for (int j = 0; j < 4; ++j) {                                       \
                    float s = aa[j];                                                \
                    float t = fminf(fmaf(s, LOG2E, -C_OFF), T_CLAMP);                \
                    S[rt][j] += __builtin_amdgcn_exp2f(t);                          \
                    P[rt][j] += (labc == labr[rt][j]) ? s : 0.f;                    \
                }                                                                   \
            }                                                                       \
        }                                                                           \
    }

    bf16x8 bA[8], bB[8];
#pragma unroll
    for (int kf = 0; kf < 8; ++kf)
        bA[kf] = *reinterpret_cast<const bf16x8*>(bptr + kf * 32);

    for (int it = 0; it < 32; ++it) {
        int kb0 = it * 2;
        const unsigned short* p1 = bptr + (size_t)(kb0 + 1) * (16 * D_N);
#pragma unroll
        for (int kf = 0; kf < 8; ++kf)
            bB[kf] = *reinterpret_cast<const bf16x8*>(p1 + kf * 32);
        PROCESS(kb0, bA);
        if (it < 31) {
            const unsigned short* p2 = bptr + (size_t)(kb0 + 2) * (16 * D_N);
#pragma unroll
            for (int kf = 0; kf < 8; ++kf)
                bA[kf] = *reinterpret_cast<const bf16x8*>(p2 + kf * 32);
        }
        PROCESS(kb0 + 1, bB);
    }
#undef PROCESS

    // sum across the 16 col-lanes (lanes sharing lk hold the same rows)
#pragma unroll
    for (int rt = 0; rt < 2; ++rt)
#pragma unroll
        for (int j = 0; j < 4; ++j) {
            float sv = S[rt][j], pv = P[rt][j];
#pragma unroll
            for (int msk = 1; msk < 16; msk <<= 1) {
                sv += __shfl_xor(sv, msk);
                pv += __shfl_xor(pv, msk);
            }
            if (lr == 0) {
                int rl = rt * 16 + lk * 4 + j;
                float2 q; q.x = sv; q.y = pv;
                partials[(size_t)(((m * 32 + rb) * 8 + ns) * 128) + wave * 32 + rl] = q;
            }
        }
}

// one thread per (m,i): merge 8 col-split partials, finish the loss term
__global__ void reduce_kernel(const float2* __restrict__ partials,
                              const float* __restrict__ norm2,
                              const int* __restrict__ labels,
                              const int* __restrict__ hist,
                              float* __restrict__ blockpart) {
    int gid = blockIdx.x * 256 + threadIdx.x;   // 12288
    int m = gid >> 12, i = gid & 4095;
    int rb = i >> 7, r = i & 127;
    const float2* pp = partials + (size_t)(((m * 32 + rb) * 8) * 128) + r;
    float S = 0.f, P = 0.f;
#pragma unroll
    for (int ns = 0; ns < 8; ++ns) {
        float2 q = pp[ns * 128];
        S += q.x; P += q.y;
    }
    P -= norm2[gid];                       // remove self-sim from positive sum
    int pc = hist[labels[i]] - 1;
    float contrib = (pc > 0)
        ? (__builtin_amdgcn_logf(S) + C_OFF) * LN2 - P / (float)pc
        : 0.f;
#pragma unroll
    for (int off = 32; off >= 1; off >>= 1) contrib += __shfl_down(contrib, off);
    __shared__ float w4[4];
    if ((threadIdx.x & 63) == 0) w4[threadIdx.x >> 6] = contrib;
    __syncthreads();
    if (threadIdx.x == 0) blockpart[blockIdx.x] = w4[0] + w4[1] + w4[2] + w4[3];
}

__global__ void final_kernel(const float* __restrict__ blockpart, const int* __restrict__ nv,
                             float* __restrict__ out) {
    int lane = threadIdx.x;
    float s = (lane < 48) ? blockpart[lane] : 0.f;
#pragma unroll
    for (int off = 32; off >= 1; off >>= 1) s += __shfl_down(s, off);
    if (lane == 0) out[0] = s / (float)(nv[0] * M_N);
}

extern "C" void kernel_launch(void* const* d_in, const int* in_sizes, int n_in,
                              void* d_out, int out_size, void* d_ws, size_t ws_size,
                              hipStream_t stream) {
    const float* tokens = (const float*)d_in[0];
    const int*   labels = (const int*)d_in[1];
    float* out = (float*)d_out;

    char* ws = (char*)d_ws;
    int*    hist      = (int*)ws;                           // 32 ints
    int*    nv        = (int*)(ws + 128);                   // 1 int
    float*  blockpart = (float*)(ws + 256);                 // 48 floats
    float*  norm2     = (float*)(ws + 1024);                // 12288 floats
    float2* partials  = (float2*)(ws + 65536);              // 768*128 float2 = 786 KB
    unsigned short* tokb = (unsigned short*)(ws + 1048576); // 6.29 MB

    cvt_kernel<<<3072, 256, 0, stream>>>(tokens, tokb, norm2);
    hist_kernel<<<1, 256, 0, stream>>>(labels, hist, nv);
    main_kernel<<<768, 256, 0, stream>>>(tokb, labels, partials);
    reduce_kernel<<<48, 256, 0, stream>>>(partials, norm2, labels, hist, blockpart);
    final_kernel<<<1, 64, 0, stream>>>(blockpart, nv, out);
}

// Round 4
// 56.910 us; speedup vs baseline: 3.5249x; 3.5249x over previous
//
#include <hip/hip_runtime.h>

#define B_N 4096
#define M_N 3
#define D_N 256
#define LOG2E 1.44269504088896340736f
#define LN2   0.69314718055994530942f
#define C_OFF   64.0f
#define T_CLAMP 112.0f

typedef __bf16 bf16x8 __attribute__((ext_vector_type(8)));
typedef float  f32x4  __attribute__((ext_vector_type(4)));

__device__ __forceinline__ unsigned short f2bf(float f) {
    unsigned int u = __float_as_uint(f);
    u += 0x7FFFu + ((u >> 16) & 1u);   // round-to-nearest-even
    return (unsigned short)(u >> 16);
}
__device__ __forceinline__ float bf2f(unsigned short h) {
    return __uint_as_float(((unsigned int)h) << 16);
}

// tokens [i][m][d] f32 -> tokb [m][i][d] bf16; norm2[m*B+i] = sum(bf16(x)^2) fp32
__global__ void cvt_kernel(const float* __restrict__ in, unsigned short* __restrict__ out,
                           float* __restrict__ norm2) {
    int idx = blockIdx.x * blockDim.x + threadIdx.x;   // 786432 float4s
    float4 v = reinterpret_cast<const float4*>(in)[idx];
    int i   = idx / 192;            // 192 = M*D/4
    int rem = idx - i * 192;
    int m   = rem >> 6;
    int d4  = rem & 63;
    ushort4 o;
    o.x = f2bf(v.x); o.y = f2bf(v.y); o.z = f2bf(v.z); o.w = f2bf(v.w);
    reinterpret_cast<ushort4*>(out)[((size_t)m * B_N + i) * 64 + d4] = o;
    float nx = bf2f(o.x), ny = bf2f(o.y), nz = bf2f(o.z), nw = bf2f(o.w);
    float s = nx * nx + ny * ny + nz * nz + nw * nw;
#pragma unroll
    for (int msk = 1; msk < 64; msk <<= 1) s += __shfl_xor(s, msk);
    if ((threadIdx.x & 63) == 0) norm2[m * B_N + i] = s;  // wave spans one (i,m) row
}

__global__ void hist_kernel(const int* __restrict__ labels, int* __restrict__ hist,
                            int* __restrict__ nvout) {
    __shared__ int h[32];
    __shared__ int nv;
    int tid = threadIdx.x;
    if (tid < 32) h[tid] = 0;
    if (tid == 0) nv = 0;
    __syncthreads();
    for (int i = tid; i < B_N; i += 256) atomicAdd(&h[labels[i]], 1);
    __syncthreads();
    int cnt = 0;
    for (int i = tid; i < B_N; i += 256) cnt += (h[labels[i]] >= 2) ? 1 : 0;
    atomicAdd(&nv, cnt);
    __syncthreads();
    if (tid < 32) hist[tid] = h[tid];
    if (tid == 0) nvout[0] = nv;
}

// Block: 128 rows x 512 cols of one modality; 4 waves x 32 rows.
// B tile (16 cols x 256 d = 8 KB) shared across waves via LDS, double-buffered.
// Staging: global->reg->ds_write (linear, conflict-free), XOR-swizzled chunk
// placement; ds_read_b128 applies the same XOR -> ~2-way (free) on reads.
// grid = 3m x 8ns x 32rb = 768 blocks, all co-resident.
__global__ __launch_bounds__(256, 3) void main_kernel(
    const unsigned short* __restrict__ tokb, const int* __restrict__ labels,
    float2* __restrict__ partials) {
    int raw = blockIdx.x;
    int bid = (raw & 7) * 96 + (raw >> 3);   // bijective XCD swizzle (768 % 8 == 0)
    int m  = bid >> 8;
    int ns = (bid >> 5) & 7;
    int rb = bid & 31;
    int i0 = rb * 128;
    int cb = ns * 512;

    int tid  = threadIdx.x;
    int wave = tid >> 6, lane = tid & 63;
    int lr = lane & 15, lk = lane >> 4;
    const unsigned short* tm = tokb + (size_t)m * (B_N * D_N);

    __shared__ __align__(16) char ldsB[2][8192];
    __shared__ int labl[512];
    labl[tid]       = labels[cb + tid];
    labl[tid + 256] = labels[cb + tid + 256];

    // A fragments: rows r0 + rt*16 + lr, registers for whole kernel
    int r0 = i0 + wave * 32;
    bf16x8 afrag[2][8];
#pragma unroll
    for (int rt = 0; rt < 2; ++rt) {
        const unsigned short* rp = tm + (size_t)(r0 + rt * 16 + lr) * D_N + lk * 8;
#pragma unroll
        for (int kf = 0; kf < 8; ++kf)
            afrag[rt][kf] = *reinterpret_cast<const bf16x8*>(rp + kf * 32);
    }
    int labr[2][4];
#pragma unroll
    for (int rt = 0; rt < 2; ++rt)
#pragma unroll
        for (int j = 0; j < 4; ++j)
            labr[rt][j] = labels[r0 + rt * 16 + lk * 4 + j];

    float S[2][4] = {{0.f, 0.f, 0.f, 0.f}, {0.f, 0.f, 0.f, 0.f}};
    float P[2][4] = {{0.f, 0.f, 0.f, 0.f}, {0.f, 0.f, 0.f, 0.f}};

    // Staging map: thread (lc = tid>>5 in 0..7, w = tid&31) loads source chunk
    // sch = w ^ (lc&7) of cols (cb+lc) and (cb+lc+8), writes LDS linearly at
    // tid*16 and 4096+tid*16.  => LDS[col*512 + w*16] = global[col][w ^ (col&7)]
    int lc  = tid >> 5;
    int w   = tid & 31;
    int sch = w ^ (lc & 7);
    const unsigned short* sbase = tm + (size_t)(cb + lc) * D_N + sch * 8;

    // prologue: tile 0 -> regs -> buf 0
    {
        bf16x8 t0 = *reinterpret_cast<const bf16x8*>(sbase);
        bf16x8 t1 = *reinterpret_cast<const bf16x8*>(sbase + 8 * D_N);
        *reinterpret_cast<bf16x8*>(&ldsB[0][tid * 16])        = t0;
        *reinterpret_cast<bf16x8*>(&ldsB[0][4096 + tid * 16]) = t1;
    }

    for (int kb = 0; kb < 32; ++kb) {
        int cur = kb & 1;
        __syncthreads();   // buf[cur] staged; all reads of buf[cur^1] drained

        // issue next-tile global loads early (T14: latency hides under compute)
        int nkb = (kb + 1) & 31;   // wrap: last-iter load/write is dead but safe
        const unsigned short* np = sbase + (size_t)nkb * (16 * D_N);
        bf16x8 nt0 = *reinterpret_cast<const bf16x8*>(np);
        bf16x8 nt1 = *reinterpret_cast<const bf16x8*>(np + 8 * D_N);

        const char* bp = ldsB[cur];
        int swz = (lr & 7) << 4;
        bf16x8 bfrag[8];
#pragma unroll
        for (int kf = 0; kf < 8; ++kf)
            bfrag[kf] = *reinterpret_cast<const bf16x8*>(
                bp + lr * 512 + ((((kf * 4 + lk) << 4)) ^ swz));
        int labc = labl[kb * 16 + lr];

        f32x4 acc0 = {0.f, 0.f, 0.f, 0.f};
        f32x4 acc1 = {0.f, 0.f, 0.f, 0.f};
#pragma unroll
        for (int kf = 0; kf < 8; ++kf) {
            acc0 = __builtin_amdgcn_mfma_f32_16x16x32_bf16(afrag[0][kf], bfrag[kf], acc0, 0, 0, 0);
            acc1 = __builtin_amdgcn_mfma_f32_16x16x32_bf16(afrag[1][kf], bfrag[kf], acc1, 0, 0, 0);
        }

        int cg0 = cb + kb * 16;
        if ((cg0 < r0 + 32) && (cg0 + 16 > r0)) {
            int colg = cg0 + lr;
#pragma unroll
            for (int rt = 0; rt < 2; ++rt) {
                f32x4 aa = rt ? acc1 : acc0;
#pragma unroll
                for (int j = 0; j < 4; ++j) {
                    float s = aa[j];
                    float t = fminf(fmaf(s, LOG2E, -C_OFF), T_CLAMP);
                    float e = __builtin_amdgcn_exp2f(t);
                    int row = r0 + rt * 16 + lk * 4 + j;
                    e = (colg == row) ? 0.f : e;   // exclude self from partition
                    S[rt][j] += e;
                    P[rt][j] += (labc == labr[rt][j]) ? s : 0.f;  // diag in, -norm2 later
                }
            }
        } else {
#pragma unroll
            for (int rt = 0; rt < 2; ++rt) {
                f32x4 aa = rt ? acc1 : acc0;
#pragma unroll
                for (int j = 0; j < 4; ++j) {
                    float s = aa[j];
                    float t = fminf(fmaf(s, LOG2E, -C_OFF), T_CLAMP);
                    S[rt][j] += __builtin_amdgcn_exp2f(t);
                    P[rt][j] += (labc == labr[rt][j]) ? s : 0.f;
                }
            }
        }

        // write next tile (other buffer); barrier at loop top publishes it
        char* dst = (char*)ldsB[cur ^ 1];
        *reinterpret_cast<bf16x8*>(dst + tid * 16)        = nt0;
        *reinterpret_cast<bf16x8*>(dst + 4096 + tid * 16) = nt1;
    }

    // sum across the 16 col-lanes (lanes sharing lk hold the same rows)
#pragma unroll
    for (int rt = 0; rt < 2; ++rt)
#pragma unroll
        for (int j = 0; j < 4; ++j) {
            float sv = S[rt][j], pv = P[rt][j];
#pragma unroll
            for (int msk = 1; msk < 16; msk <<= 1) {
                sv += __shfl_xor(sv, msk);
                pv += __shfl_xor(pv, msk);
            }
            if (lr == 0) {
                int rl = rt * 16 + lk * 4 + j;
                float2 q; q.x = sv; q.y = pv;
                partials[(size_t)(((m * 32 + rb) * 8 + ns) * 128) + wave * 32 + rl] = q;
            }
        }
}

// one thread per (m,i): merge 8 col-split partials, finish the loss term
__global__ void reduce_kernel(const float2* __restrict__ partials,
                              const float* __restrict__ norm2,
                              const int* __restrict__ labels,
                              const int* __restrict__ hist,
                              float* __restrict__ blockpart) {
    int gid = blockIdx.x * 256 + threadIdx.x;   // 12288
    int m = gid >> 12, i = gid & 4095;
    int rb = i >> 7, r = i & 127;
    const float2* pp = partials + (size_t)(((m * 32 + rb) * 8) * 128) + r;
    float S = 0.f, P = 0.f;
#pragma unroll
    for (int ns = 0; ns < 8; ++ns) {
        float2 q = pp[ns * 128];
        S += q.x; P += q.y;
    }
    P -= norm2[gid];                       // remove self-sim from positive sum
    int pc = hist[labels[i]] - 1;
    float contrib = (pc > 0)
        ? (__builtin_amdgcn_logf(S) + C_OFF) * LN2 - P / (float)pc
        : 0.f;
#pragma unroll
    for (int off = 32; off >= 1; off >>= 1) contrib += __shfl_down(contrib, off);
    __shared__ float w4[4];
    if ((threadIdx.x & 63) == 0) w4[threadIdx.x >> 6] = contrib;
    __syncthreads();
    if (threadIdx.x == 0) blockpart[blockIdx.x] = w4[0] + w4[1] + w4[2] + w4[3];
}

__global__ void final_kernel(const float* __restrict__ blockpart, const int* __restrict__ nv,
                             float* __restrict__ out) {
    int lane = threadIdx.x;
    float s = (lane < 48) ? blockpart[lane] : 0.f;
#pragma unroll
    for (int off = 32; off >= 1; off >>= 1) s += __shfl_down(s, off);
    if (lane == 0) out[0] = s / (float)(nv[0] * M_N);
}

extern "C" void kernel_launch(void* const* d_in, const int* in_sizes, int n_in,
                              void* d_out, int out_size, void* d_ws, size_t ws_size,
                              hipStream_t stream) {
    const float* tokens = (const float*)d_in[0];
    const int*   labels = (const int*)d_in[1];
    float* out = (float*)d_out;

    char* ws = (char*)d_ws;
    int*    hist      = (int*)ws;                           // 32 ints
    int*    nv        = (int*)(ws + 128);                   // 1 int
    float*  blockpart = (float*)(ws + 256);                 // 48 floats
    float*  norm2     = (float*)(ws + 1024);                // 12288 floats
    float2* partials  = (float2*)(ws + 65536);              // 768*128 float2 = 786 KB
    unsigned short* tokb = (unsigned short*)(ws + 1048576); // 6.29 MB

    cvt_kernel<<<3072, 256, 0, stream>>>(tokens, tokb, norm2);
    hist_kernel<<<1, 256, 0, stream>>>(labels, hist, nv);
    main_kernel<<<768, 256, 0, stream>>>(tokb, labels, partials);
    reduce_kernel<<<48, 256, 0, stream>>>(partials, norm2, labels, hist, blockpart);
    final_kernel<<<1, 64, 0, stream>>>(blockpart, nv, out);
}